// Round 1
// baseline (1107.031 us; speedup 1.0000x reference)
//
#include <hip/hip_runtime.h>
#include <hip/hip_bf16.h>

#define NN 126   // nodes
#define TT 24    // seq len
#define FF 17    // input feat
#define HH 100   // hidden
#define BH 32    // batches per workgroup (64 split across 2 WGs per node)
#define BPG 8    // batches per thread (batch-group)
#define NTH 448  // threads per block: 100 j * 4 groups = 400 active, pad to 7 waves

__device__ __forceinline__ float sigm(float x) {
    return 1.0f / (1.0f + __expf(-x));
}
__device__ __forceinline__ float tanh_f(float x) {
    x = fminf(fmaxf(x, -15.0f), 15.0f);   // saturates anyway; avoids inf/inf
    float e = __expf(2.0f * x);
    return (e - 1.0f) / (e + 1.0f);
}

__global__ __launch_bounds__(NTH, 1)
void lstm_fused(const float* __restrict__ x,
                const float* __restrict__ Wih0, const float* __restrict__ Whh0,
                const float* __restrict__ bih0, const float* __restrict__ bhh0,
                const float* __restrict__ Wih1, const float* __restrict__ Whh1,
                const float* __restrict__ bih1, const float* __restrict__ bhh1,
                const float* __restrict__ wlin, const float* __restrict__ blin,
                const float* __restrict__ wend, const float* __restrict__ bend,
                float* __restrict__ out)
{
    const int n   = blockIdx.x >> 1;
    const int b0  = (blockIdx.x & 1) * BH;     // global batch offset of this WG
    const int tid = threadIdx.x;
    const int j   = tid >> 2;                  // hidden cell index 0..99 (tid<400)
    const int bg  = tid & 3;                   // batch group 0..3
    const int bl0 = bg * BPG;                  // local batch offset
    const bool act = (j < HH);

    // h stored transposed [k][b] so dot-product reads are contiguous float4
    __shared__ float h1t[HH][BH];
    __shared__ float h2t[HH][BH];
    __shared__ float xt[FF][BH];
    __shared__ float red[HH][BH];

    for (int idx = tid; idx < HH * BH; idx += NTH) {
        (&h1t[0][0])[idx] = 0.0f;
        (&h2t[0][0])[idx] = 0.0f;
    }

    float c1[BPG], c2[BPG], macc[BPG];
    #pragma unroll
    for (int q = 0; q < BPG; ++q) { c1[q] = 0.0f; c2[q] = 0.0f; macc[q] = 0.0f; }

    // per-thread weight row pointers + fused biases (hoisted out of the t-loop)
    float bs0[4], bs1[4];
    const float* wx0r[4];
    const float* w0r[4];
    const float* wi1r[4];
    const float* w1r[4];
    if (act) {
        #pragma unroll
        for (int g = 0; g < 4; ++g) {
            const int row = n * 400 + g * HH + j;   // gate order i,f,g,o
            bs0[g] = bih0[row] + bhh0[row];
            bs1[g] = bih1[row] + bhh1[row];
            wx0r[g] = Wih0 + (size_t)row * FF;
            w0r[g]  = Whh0 + (size_t)row * HH;
            wi1r[g] = Wih1 + (size_t)row * HH;
            w1r[g]  = Whh1 + (size_t)row * HH;
        }
    }
    __syncthreads();

    for (int t = 0; t < TT; ++t) {
        // stage x_t transposed [f][b]
        for (int idx = tid; idx < FF * BH; idx += NTH) {
            const int f = idx >> 5, bl = idx & 31;
            xt[f][bl] = x[(((b0 + bl) * TT + t) * NN + n) * FF + f];
        }
        __syncthreads();

        float ga[4][BPG];
        // ---------------- layer 0 gates ----------------
        if (act) {
            #pragma unroll
            for (int g = 0; g < 4; ++g)
                #pragma unroll
                for (int q = 0; q < BPG; ++q) ga[g][q] = bs0[g];

            for (int f = 0; f < FF; ++f) {
                float w[4];
                #pragma unroll
                for (int g = 0; g < 4; ++g) w[g] = wx0r[g][f];
                #pragma unroll
                for (int q = 0; q < BPG; ++q) {
                    const float xv = xt[f][bl0 + q];
                    #pragma unroll
                    for (int g = 0; g < 4; ++g) ga[g][q] = fmaf(w[g], xv, ga[g][q]);
                }
            }
            for (int k = 0; k < HH; k += 4) {
                float wg[4][4];
                #pragma unroll
                for (int g = 0; g < 4; ++g) {
                    const float4 wv = *(const float4*)(w0r[g] + k);
                    wg[g][0] = wv.x; wg[g][1] = wv.y; wg[g][2] = wv.z; wg[g][3] = wv.w;
                }
                #pragma unroll
                for (int kk = 0; kk < 4; ++kk) {
                    const float4* hr = (const float4*)(&h1t[k + kk][bl0]);
                    const float4 ha = hr[0], hb = hr[1];
                    const float hv[BPG] = {ha.x, ha.y, ha.z, ha.w, hb.x, hb.y, hb.z, hb.w};
                    #pragma unroll
                    for (int q = 0; q < BPG; ++q)
                        #pragma unroll
                        for (int g = 0; g < 4; ++g)
                            ga[g][q] = fmaf(wg[g][kk], hv[q], ga[g][q]);
                }
            }
        }
        __syncthreads();   // all reads of h1t(old) done

        if (act) {
            #pragma unroll
            for (int q = 0; q < BPG; ++q) {
                const float iv = sigm(ga[0][q]);
                const float fv = sigm(ga[1][q]);
                const float gv = tanh_f(ga[2][q]);
                const float ov = sigm(ga[3][q]);
                const float c  = fv * c1[q] + iv * gv;
                c1[q] = c;
                h1t[j][bl0 + q] = ov * tanh_f(c);
            }
        }
        __syncthreads();   // h1t(new) visible

        // ---------------- layer 1 gates ----------------
        if (act) {
            #pragma unroll
            for (int g = 0; g < 4; ++g)
                #pragma unroll
                for (int q = 0; q < BPG; ++q) ga[g][q] = bs1[g];

            for (int k = 0; k < HH; k += 4) {
                float wg[4][4];
                #pragma unroll
                for (int g = 0; g < 4; ++g) {
                    const float4 wv = *(const float4*)(wi1r[g] + k);
                    wg[g][0] = wv.x; wg[g][1] = wv.y; wg[g][2] = wv.z; wg[g][3] = wv.w;
                }
                #pragma unroll
                for (int kk = 0; kk < 4; ++kk) {
                    const float4* hr = (const float4*)(&h1t[k + kk][bl0]);
                    const float4 ha = hr[0], hb = hr[1];
                    const float hv[BPG] = {ha.x, ha.y, ha.z, ha.w, hb.x, hb.y, hb.z, hb.w};
                    #pragma unroll
                    for (int q = 0; q < BPG; ++q)
                        #pragma unroll
                        for (int g = 0; g < 4; ++g)
                            ga[g][q] = fmaf(wg[g][kk], hv[q], ga[g][q]);
                }
            }
            for (int k = 0; k < HH; k += 4) {
                float wg[4][4];
                #pragma unroll
                for (int g = 0; g < 4; ++g) {
                    const float4 wv = *(const float4*)(w1r[g] + k);
                    wg[g][0] = wv.x; wg[g][1] = wv.y; wg[g][2] = wv.z; wg[g][3] = wv.w;
                }
                #pragma unroll
                for (int kk = 0; kk < 4; ++kk) {
                    const float4* hr = (const float4*)(&h2t[k + kk][bl0]);
                    const float4 ha = hr[0], hb = hr[1];
                    const float hv[BPG] = {ha.x, ha.y, ha.z, ha.w, hb.x, hb.y, hb.z, hb.w};
                    #pragma unroll
                    for (int q = 0; q < BPG; ++q)
                        #pragma unroll
                        for (int g = 0; g < 4; ++g)
                            ga[g][q] = fmaf(wg[g][kk], hv[q], ga[g][q]);
                }
            }
        }
        __syncthreads();   // all reads of h2t(old) done

        const float wet = wend[t];
        if (act) {
            #pragma unroll
            for (int q = 0; q < BPG; ++q) {
                const float iv = sigm(ga[0][q]);
                const float fv = sigm(ga[1][q]);
                const float gv = tanh_f(ga[2][q]);
                const float ov = sigm(ga[3][q]);
                const float c  = fv * c2[q] + iv * gv;
                c2[q] = c;
                const float h = ov * tanh_f(c);
                h2t[j][bl0 + q] = h;
                macc[q] = fmaf(wet, h, macc[q]);   // Σ_t w_end[t] * h2[t,b,j]
            }
        }
        // no trailing barrier needed: next write to h2t is 3 barriers away
    }

    // ---------------- epilogue: hn, cn, out ----------------
    if (act) {
        #pragma unroll
        for (int q = 0; q < BPG; ++q) {
            const int b = b0 + bl0 + q;
            const size_t hbase = 8064 + (size_t)n * 12800 + (size_t)b * HH + j;
            out[hbase]                  = h1t[j][bl0 + q];   // hn layer 0
            out[hbase + 6400]           = h2t[j][bl0 + q];   // hn layer 1
            out[hbase + 1612800]        = c1[q];             // cn layer 0
            out[hbase + 6400 + 1612800] = c2[q];             // cn layer 1
            red[j][bl0 + q] = wlin[j] * macc[q];
        }
    }
    __syncthreads();
    if (tid < BH) {
        float s = 0.0f;
        for (int jj = 0; jj < HH; ++jj) s += red[jj][tid];
        float ws = 0.0f;
        for (int t2 = 0; t2 < TT; ++t2) ws += wend[t2];
        s += blin[0] * ws + bend[0];
        out[(size_t)(b0 + tid) * NN + n] = s;   // out[b,0,n,0]
    }
}

extern "C" void kernel_launch(void* const* d_in, const int* in_sizes, int n_in,
                              void* d_out, int out_size, void* d_ws, size_t ws_size,
                              hipStream_t stream) {
    const float* x    = (const float*)d_in[0];
    const float* Wih0 = (const float*)d_in[1];
    const float* Whh0 = (const float*)d_in[2];
    const float* bih0 = (const float*)d_in[3];
    const float* bhh0 = (const float*)d_in[4];
    const float* Wih1 = (const float*)d_in[5];
    const float* Whh1 = (const float*)d_in[6];
    const float* bih1 = (const float*)d_in[7];
    const float* bhh1 = (const float*)d_in[8];
    const float* wlin = (const float*)d_in[9];
    const float* blin = (const float*)d_in[10];
    const float* wend = (const float*)d_in[11];
    const float* bend = (const float*)d_in[12];

    lstm_fused<<<dim3(NN * 2), dim3(NTH), 0, stream>>>(
        x, Wih0, Whh0, bih0, bhh0, Wih1, Whh1, bih1, bhh1,
        wlin, blin, wend, bend, (float*)d_out);
}

// Round 2
// 714.024 us; speedup vs baseline: 1.5504x; 1.5504x over previous
//
#include <hip/hip_runtime.h>
#include <hip/hip_bf16.h>

#define NN 126   // nodes
#define TT 24    // seq len
#define FF 17    // input feat
#define HH 100   // hidden

// ---------- MFMA fragment geometry ----------
// Gate rows are interleaved: padded row gr = cell*4 + gate, cells padded 100->112,
// rows padded 400->448 = 28 M-tiles of 16.  K layouts (bias rides as a ones-column):
//  layer0 (5 k-tiles, K=160): [x: k 0..16][ones k=17][0][h1: k 32..131][0]
//  layer1 (8 k-tiles, K=256): [h1: k 0..99][ones k=100][0][h2: k 128..227][0]
#define MT 28
#define KT0 5
#define KT1 8
#define KTALL 13
#define WFRAG_PER_NODE (KTALL * MT * 64 * 8)            // 186368 bf16
#define WFRAG_ELEMS ((size_t)NN * WFRAG_PER_NODE)       // 23,482,368
#define XFRAG_ELEMS ((size_t)NN * TT * 4 * 64 * 8)      // 6,193,152
#define WS_NEEDED ((WFRAG_ELEMS + XFRAG_ELEMS) * 2)     // 59,351,040 B

typedef __attribute__((ext_vector_type(8))) short short8v;
typedef __attribute__((ext_vector_type(4))) float float4v;

__device__ __forceinline__ short f2bf(float f) {
    union { float f; unsigned u; } v; v.f = f;
    unsigned r = v.u + 0x7FFFu + ((v.u >> 16) & 1u);   // RNE
    return (short)(r >> 16);
}
__device__ __forceinline__ float sigmf(float x) { return 1.0f / (1.0f + __expf(-x)); }
__device__ __forceinline__ float tanhf_(float x) { return 2.0f / (1.0f + __expf(-2.0f * x)) - 1.0f; }

// ---------------- prep: weights -> bf16 MFMA A-fragments ----------------
// wfrag[n][kt 0..12][mt 0..27][lane 0..63][e 0..7]
__global__ void prep_w(const float* __restrict__ Wih0, const float* __restrict__ Whh0,
                       const float* __restrict__ bih0, const float* __restrict__ bhh0,
                       const float* __restrict__ Wih1, const float* __restrict__ Whh1,
                       const float* __restrict__ bih1, const float* __restrict__ bhh1,
                       short* __restrict__ wfrag)
{
    const int idx = blockIdx.x * 256 + threadIdx.x;      // one thread per (n,kt,mt,lane)
    if (idx >= NN * KTALL * MT * 64) return;
    const int lane = idx & 63;
    int r = idx >> 6;
    const int mt = r % MT; r /= MT;
    const int kt = r % KTALL;
    const int n  = r / KTALL;

    const int row16 = lane & 15, kq = lane >> 4;
    const int gr = mt * 16 + row16;
    const int cell = gr >> 2, g = gr & 3;
    const bool real = (cell < HH);
    const int orow = n * 400 + g * HH + cell;            // original gate row (i,f,g,o blocks)

    short v[8];
    #pragma unroll
    for (int e = 0; e < 8; ++e) {
        float f = 0.0f;
        if (real) {
            if (kt < KT0) {
                const int k = kt * 32 + kq * 8 + e;
                if (k < FF)                f = Wih0[(size_t)orow * FF + k];
                else if (k == FF)          f = bih0[orow] + bhh0[orow];
                else if (k >= 32 && k < 32 + HH) f = Whh0[(size_t)orow * HH + (k - 32)];
            } else {
                const int k = (kt - KT0) * 32 + kq * 8 + e;
                if (k < HH)                f = Wih1[(size_t)orow * HH + k];
                else if (k == HH)          f = bih1[orow] + bhh1[orow];
                else if (k >= 128 && k < 128 + HH) f = Whh1[(size_t)orow * HH + (k - 128)];
            }
        }
        v[e] = f2bf(f);
    }
    short8v pv;
    #pragma unroll
    for (int e = 0; e < 8; ++e) pv[e] = v[e];
    *(short8v*)(wfrag + (size_t)idx * 8) = pv;
}

// ---------------- prep: x -> bf16 B-fragments ----------------
// xfrag[n][t][bq 0..3][lane][e]; k = (lane>>4)*8+e: k<17 -> x, k==17 -> 1.0 (bias col)
__global__ void prep_x(const float* __restrict__ x, short* __restrict__ xfrag)
{
    const int idx = blockIdx.x * 256 + threadIdx.x;      // one thread per (n,t,bq,lane)
    if (idx >= NN * TT * 4 * 64) return;
    const int lane = idx & 63;
    int r = idx >> 6;
    const int bq = r & 3; r >>= 2;
    const int t = r % TT;
    const int n = r / TT;
    const int b = bq * 16 + (lane & 15);
    const int kq = lane >> 4;

    short8v pv;
    #pragma unroll
    for (int e = 0; e < 8; ++e) {
        const int k = kq * 8 + e;
        float f = 0.0f;
        if (k < FF)       f = x[(((size_t)b * TT + t) * NN + n) * FF + k];
        else if (k == FF) f = 1.0f;
        pv[e] = f2bf(f);
    }
    *(short8v*)(xfrag + (size_t)idx * 8) = pv;
}

// ---------------- main MFMA LSTM ----------------
template<int KTBASE, int NKT>
__device__ __forceinline__ void mfma_phase(const short* __restrict__ wbl,
                                           const short (*Xf)[2][64][8],
                                           int nh, int lane, float4v acc[7])
{
    short8v af[7];
    #pragma unroll
    for (int ti = 0; ti < 7; ++ti)
        af[ti] = *(const short8v*)(wbl + ((size_t)KTBASE * MT + ti) * 512);
    #pragma unroll
    for (int kt = 0; kt < NKT; ++kt) {
        const short8v bfv = *(const short8v*)(&Xf[kt][nh][lane][0]);
        short8v afn[7];
        if (kt + 1 < NKT) {
            #pragma unroll
            for (int ti = 0; ti < 7; ++ti)
                afn[ti] = *(const short8v*)(wbl + ((size_t)(KTBASE + kt + 1) * MT + ti) * 512);
        }
        #pragma unroll
        for (int ti = 0; ti < 7; ++ti)
            acc[ti] = __builtin_amdgcn_mfma_f32_16x16x32_bf16(af[ti], bfv, acc[ti], 0, 0, 0);
        if (kt + 1 < NKT) {
            #pragma unroll
            for (int ti = 0; ti < 7; ++ti) af[ti] = afn[ti];
        }
    }
}

__global__ __launch_bounds__(512, 2)
void lstm_mfma(const short* __restrict__ wfrag, const short* __restrict__ xfrag,
               const float* __restrict__ wlin, const float* __restrict__ blin,
               const float* __restrict__ wend, const float* __restrict__ bend,
               float* __restrict__ out)
{
    const int n  = blockIdx.x >> 1;
    const int bh = blockIdx.x & 1;          // batch half (32 each)
    const int tid = threadIdx.x;
    const int lane = tid & 63;
    const int w = tid >> 6;                 // 8 waves
    const int mq = w >> 1;                  // M-quarter 0..3 (7 M-tiles each)
    const int nh = w & 1;                   // batch 16-group within the half
    const int cl = lane & 15;               // batch col within tile
    const int q  = lane >> 4;

    __shared__ __align__(16) short Xf0[KT0][2][64][8];
    __shared__ __align__(16) short Xf1[KT1][2][64][8];
    __shared__ float red[HH][32];

    // zero-init LDS fragments (pad zones stay zero forever)
    {
        const short8v z = {0,0,0,0,0,0,0,0};
        for (int i = tid; i < KT0 * 2 * 64; i += 512) *(short8v*)(&Xf0[0][0][0][0] + (size_t)i * 8) = z;
        for (int i = tid; i < KT1 * 2 * 64; i += 512) *(short8v*)(&Xf1[0][0][0][0] + (size_t)i * 8) = z;
    }
    __syncthreads();
    // ones column for layer1 bias (k=100 -> kt=3, kq=0, e=4); x(t=0) carries layer0's ones
    if (tid < 32) Xf1[3][tid >> 4][tid & 15][4] = (short)0x3F80;
    if (mq == 0)
        *(short8v*)(&Xf0[0][nh][lane][0]) =
            *(const short8v*)(xfrag + ((((size_t)n * TT + 0) * 4 + (bh * 2 + nh)) * 64 + lane) * 8);
    __syncthreads();

    float c1[7], c2[7], macc[7];
    #pragma unroll
    for (int ti = 0; ti < 7; ++ti) { c1[ti] = 0.0f; c2[ti] = 0.0f; macc[ti] = 0.0f; }

    const short* wbl = wfrag + (size_t)n * WFRAG_PER_NODE + (size_t)(mq * 7) * 512 + (size_t)lane * 8;
    const int b = bh * 32 + nh * 16 + cl;   // global batch of this lane

    for (int t = 0; t < TT; ++t) {
        float4v acc[7];
        #pragma unroll
        for (int ti = 0; ti < 7; ++ti) acc[ti] = (float4v){0.f, 0.f, 0.f, 0.f};
        mfma_phase<0, KT0>(wbl, Xf0, nh, lane, acc);
        __syncthreads();                    // A: all Xf0 reads done

        // -------- layer 0 activation (lane owns cell's 4 gates in acc regs) --------
        #pragma unroll
        for (int ti = 0; ti < 7; ++ti) {
            const int mt = mq * 7 + ti;
            if (mt < 25) {                  // real cells only (wave-uniform)
                const int cell = mt * 4 + q;
                const float iv = sigmf(acc[ti][0]);
                const float fv = sigmf(acc[ti][1]);
                const float gv = tanhf_(acc[ti][2]);
                const float ov = sigmf(acc[ti][3]);
                const float c  = fv * c1[ti] + iv * gv;
                c1[ti] = c;
                const float h = ov * tanhf_(c);
                const short hb = f2bf(h);
                { const int k = 32 + cell; Xf0[k >> 5][nh][(((k >> 3) & 3) << 4) | cl][k & 7] = hb; }
                { const int k = cell;      Xf1[k >> 5][nh][(((k >> 3) & 3) << 4) | cl][k & 7] = hb; }
                if (t == TT - 1) {
                    out[8064 + ((size_t)(n * 2 + 0) * 64 + b) * HH + cell] = h;
                    out[8064 + 1612800 + ((size_t)(n * 2 + 0) * 64 + b) * HH + cell] = c;
                }
            }
        }
        __syncthreads();                    // B: h1 fragments visible

        #pragma unroll
        for (int ti = 0; ti < 7; ++ti) acc[ti] = (float4v){0.f, 0.f, 0.f, 0.f};
        mfma_phase<KT0, KT1>(wbl, Xf1, nh, lane, acc);
        __syncthreads();                    // C: all Xf1 reads done

        // -------- layer 1 activation --------
        const float wet = wend[t];
        #pragma unroll
        for (int ti = 0; ti < 7; ++ti) {
            const int mt = mq * 7 + ti;
            if (mt < 25) {
                const int cell = mt * 4 + q;
                const float iv = sigmf(acc[ti][0]);
                const float fv = sigmf(acc[ti][1]);
                const float gv = tanhf_(acc[ti][2]);
                const float ov = sigmf(acc[ti][3]);
                const float c  = fv * c2[ti] + iv * gv;
                c2[ti] = c;
                const float h = ov * tanhf_(c);
                macc[ti] = fmaf(wet, h, macc[ti]);
                const int k = 128 + cell;
                Xf1[k >> 5][nh][(((k >> 3) & 3) << 4) | cl][k & 7] = f2bf(h);
                if (t == TT - 1) {
                    out[8064 + ((size_t)(n * 2 + 1) * 64 + b) * HH + cell] = h;
                    out[8064 + 1612800 + ((size_t)(n * 2 + 1) * 64 + b) * HH + cell] = c;
                }
            }
        }
        // x for t+1 into Xf0 x-tile (its reads finished before barrier A)
        if (mq == 0 && t + 1 < TT)
            *(short8v*)(&Xf0[0][nh][lane][0]) =
                *(const short8v*)(xfrag + ((((size_t)n * TT + (t + 1)) * 4 + (bh * 2 + nh)) * 64 + lane) * 8);
        __syncthreads();                    // D: h2 / x visible for next step
    }

    // -------- epilogue: out[b,0,n,0] --------
    #pragma unroll
    for (int ti = 0; ti < 7; ++ti) {
        const int mt = mq * 7 + ti;
        if (mt < 25) {
            const int cell = mt * 4 + q;
            red[cell][nh * 16 + cl] = wlin[cell] * macc[ti];
        }
    }
    __syncthreads();
    if (tid < 32) {
        float s = 0.0f;
        for (int j = 0; j < HH; ++j) s += red[j][tid];
        float ws = 0.0f;
        for (int t2 = 0; t2 < TT; ++t2) ws += wend[t2];
        s += blin[0] * ws + bend[0];
        out[(size_t)(bh * 32 + tid) * NN + n] = s;
    }
}

// ================= fallback (R1 fp32 kernel, known-good) =================
#define BH 32
#define BPG 8
#define NTH 448

__global__ __launch_bounds__(NTH, 1)
void lstm_fused(const float* __restrict__ x,
                const float* __restrict__ Wih0, const float* __restrict__ Whh0,
                const float* __restrict__ bih0, const float* __restrict__ bhh0,
                const float* __restrict__ Wih1, const float* __restrict__ Whh1,
                const float* __restrict__ bih1, const float* __restrict__ bhh1,
                const float* __restrict__ wlin, const float* __restrict__ blin,
                const float* __restrict__ wend, const float* __restrict__ bend,
                float* __restrict__ out)
{
    const int n   = blockIdx.x >> 1;
    const int b0  = (blockIdx.x & 1) * BH;
    const int tid = threadIdx.x;
    const int j   = tid >> 2;
    const int bg  = tid & 3;
    const int bl0 = bg * BPG;
    const bool act = (j < HH);

    __shared__ float h1t[HH][BH];
    __shared__ float h2t[HH][BH];
    __shared__ float xt[FF][BH];
    __shared__ float red[HH][BH];

    for (int idx = tid; idx < HH * BH; idx += NTH) {
        (&h1t[0][0])[idx] = 0.0f;
        (&h2t[0][0])[idx] = 0.0f;
    }
    float c1[BPG], c2[BPG], macc[BPG];
    #pragma unroll
    for (int q = 0; q < BPG; ++q) { c1[q] = 0.0f; c2[q] = 0.0f; macc[q] = 0.0f; }

    float bs0[4], bs1[4];
    const float* wx0r[4];
    const float* w0r[4];
    const float* wi1r[4];
    const float* w1r[4];
    if (act) {
        #pragma unroll
        for (int g = 0; g < 4; ++g) {
            const int row = n * 400 + g * HH + j;
            bs0[g] = bih0[row] + bhh0[row];
            bs1[g] = bih1[row] + bhh1[row];
            wx0r[g] = Wih0 + (size_t)row * FF;
            w0r[g]  = Whh0 + (size_t)row * HH;
            wi1r[g] = Wih1 + (size_t)row * HH;
            w1r[g]  = Whh1 + (size_t)row * HH;
        }
    }
    __syncthreads();

    for (int t = 0; t < TT; ++t) {
        for (int idx = tid; idx < FF * BH; idx += NTH) {
            const int f = idx >> 5, bl = idx & 31;
            xt[f][bl] = x[(((b0 + bl) * TT + t) * NN + n) * FF + f];
        }
        __syncthreads();

        float ga[4][BPG];
        if (act) {
            #pragma unroll
            for (int g = 0; g < 4; ++g)
                #pragma unroll
                for (int q = 0; q < BPG; ++q) ga[g][q] = bs0[g];
            for (int f = 0; f < FF; ++f) {
                float wv[4];
                #pragma unroll
                for (int g = 0; g < 4; ++g) wv[g] = wx0r[g][f];
                #pragma unroll
                for (int q = 0; q < BPG; ++q) {
                    const float xv = xt[f][bl0 + q];
                    #pragma unroll
                    for (int g = 0; g < 4; ++g) ga[g][q] = fmaf(wv[g], xv, ga[g][q]);
                }
            }
            for (int k = 0; k < HH; k += 4) {
                float wg[4][4];
                #pragma unroll
                for (int g = 0; g < 4; ++g) {
                    const float4 wv = *(const float4*)(w0r[g] + k);
                    wg[g][0] = wv.x; wg[g][1] = wv.y; wg[g][2] = wv.z; wg[g][3] = wv.w;
                }
                #pragma unroll
                for (int kk = 0; kk < 4; ++kk) {
                    const float4* hr = (const float4*)(&h1t[k + kk][bl0]);
                    const float4 ha = hr[0], hb2 = hr[1];
                    const float hv[BPG] = {ha.x, ha.y, ha.z, ha.w, hb2.x, hb2.y, hb2.z, hb2.w};
                    #pragma unroll
                    for (int q = 0; q < BPG; ++q)
                        #pragma unroll
                        for (int g = 0; g < 4; ++g)
                            ga[g][q] = fmaf(wg[g][kk], hv[q], ga[g][q]);
                }
            }
        }
        __syncthreads();
        if (act) {
            #pragma unroll
            for (int q = 0; q < BPG; ++q) {
                const float iv = sigmf(ga[0][q]);
                const float fv = sigmf(ga[1][q]);
                const float gv = tanhf_(ga[2][q]);
                const float ov = sigmf(ga[3][q]);
                const float c  = fv * c1[q] + iv * gv;
                c1[q] = c;
                h1t[j][bl0 + q] = ov * tanhf_(c);
            }
        }
        __syncthreads();
        if (act) {
            #pragma unroll
            for (int g = 0; g < 4; ++g)
                #pragma unroll
                for (int q = 0; q < BPG; ++q) ga[g][q] = bs1[g];
            for (int k = 0; k < HH; k += 4) {
                float wg[4][4];
                #pragma unroll
                for (int g = 0; g < 4; ++g) {
                    const float4 wv = *(const float4*)(wi1r[g] + k);
                    wg[g][0] = wv.x; wg[g][1] = wv.y; wg[g][2] = wv.z; wg[g][3] = wv.w;
                }
                #pragma unroll
                for (int kk = 0; kk < 4; ++kk) {
                    const float4* hr = (const float4*)(&h1t[k + kk][bl0]);
                    const float4 ha = hr[0], hb2 = hr[1];
                    const float hv[BPG] = {ha.x, ha.y, ha.z, ha.w, hb2.x, hb2.y, hb2.z, hb2.w};
                    #pragma unroll
                    for (int q = 0; q < BPG; ++q)
                        #pragma unroll
                        for (int g = 0; g < 4; ++g)
                            ga[g][q] = fmaf(wg[g][kk], hv[q], ga[g][q]);
                }
            }
            for (int k = 0; k < HH; k += 4) {
                float wg[4][4];
                #pragma unroll
                for (int g = 0; g < 4; ++g) {
                    const float4 wv = *(const float4*)(w1r[g] + k);
                    wg[g][0] = wv.x; wg[g][1] = wv.y; wg[g][2] = wv.z; wg[g][3] = wv.w;
                }
                #pragma unroll
                for (int kk = 0; kk < 4; ++kk) {
                    const float4* hr = (const float4*)(&h2t[k + kk][bl0]);
                    const float4 ha = hr[0], hb2 = hr[1];
                    const float hv[BPG] = {ha.x, ha.y, ha.z, ha.w, hb2.x, hb2.y, hb2.z, hb2.w};
                    #pragma unroll
                    for (int q = 0; q < BPG; ++q)
                        #pragma unroll
                        for (int g = 0; g < 4; ++g)
                            ga[g][q] = fmaf(wg[g][kk], hv[q], ga[g][q]);
                }
            }
        }
        __syncthreads();
        const float wet = wend[t];
        if (act) {
            #pragma unroll
            for (int q = 0; q < BPG; ++q) {
                const float iv = sigmf(ga[0][q]);
                const float fv = sigmf(ga[1][q]);
                const float gv = tanhf_(ga[2][q]);
                const float ov = sigmf(ga[3][q]);
                const float c  = fv * c2[q] + iv * gv;
                c2[q] = c;
                const float h = ov * tanhf_(c);
                h2t[j][bl0 + q] = h;
                macc[q] = fmaf(wet, h, macc[q]);
            }
        }
    }

    if (act) {
        #pragma unroll
        for (int q = 0; q < BPG; ++q) {
            const int b = b0 + bl0 + q;
            const size_t hbase = 8064 + (size_t)n * 12800 + (size_t)b * HH + j;
            out[hbase]                  = h1t[j][bl0 + q];
            out[hbase + 6400]           = h2t[j][bl0 + q];
            out[hbase + 1612800]        = c1[q];
            out[hbase + 6400 + 1612800] = c2[q];
            red[j][bl0 + q] = wlin[j] * macc[q];
        }
    }
    __syncthreads();
    if (tid < BH) {
        float s = 0.0f;
        for (int jj = 0; jj < HH; ++jj) s += red[jj][tid];
        float ws = 0.0f;
        for (int t2 = 0; t2 < TT; ++t2) ws += wend[t2];
        s += blin[0] * ws + bend[0];
        out[(size_t)(b0 + tid) * NN + n] = s;
    }
}

extern "C" void kernel_launch(void* const* d_in, const int* in_sizes, int n_in,
                              void* d_out, int out_size, void* d_ws, size_t ws_size,
                              hipStream_t stream) {
    const float* x    = (const float*)d_in[0];
    const float* Wih0 = (const float*)d_in[1];
    const float* Whh0 = (const float*)d_in[2];
    const float* bih0 = (const float*)d_in[3];
    const float* bhh0 = (const float*)d_in[4];
    const float* Wih1 = (const float*)d_in[5];
    const float* Whh1 = (const float*)d_in[6];
    const float* bih1 = (const float*)d_in[7];
    const float* bhh1 = (const float*)d_in[8];
    const float* wlin = (const float*)d_in[9];
    const float* blin = (const float*)d_in[10];
    const float* wend = (const float*)d_in[11];
    const float* bend = (const float*)d_in[12];

    if (ws_size < WS_NEEDED) {
        lstm_fused<<<dim3(NN * 2), dim3(NTH), 0, stream>>>(
            x, Wih0, Whh0, bih0, bhh0, Wih1, Whh1, bih1, bhh1,
            wlin, blin, wend, bend, (float*)d_out);
        return;
    }

    short* wfrag = (short*)d_ws;
    short* xfrag = wfrag + WFRAG_ELEMS;

    prep_w<<<dim3((NN * KTALL * MT * 64 + 255) / 256), dim3(256), 0, stream>>>(
        Wih0, Whh0, bih0, bhh0, Wih1, Whh1, bih1, bhh1, wfrag);
    prep_x<<<dim3((NN * TT * 4 * 64 + 255) / 256), dim3(256), 0, stream>>>(x, xfrag);
    lstm_mfma<<<dim3(NN * 2), dim3(512), 0, stream>>>(
        wfrag, xfrag, wlin, blin, wend, bend, (float*)d_out);
}

// Round 3
// 226.225 us; speedup vs baseline: 4.8935x; 3.1563x over previous
//
#include <hip/hip_runtime.h>
#include <hip/hip_bf16.h>

#define NN 126   // nodes
#define TT 24    // seq len
#define FF 17    // input feat
#define HH 100   // hidden

// ---------- lean MFMA fragment geometry ----------
// M: gate rows interleaved gr = cell*4 + gate -> 400 rows = exactly 25 tiles of 16.
// K layouts (bias rides as a ones-column):
//  layer0, 5 kt (K=160): kt0 = [x 0..16][ones 17][pad 18..31]; kt1..4 = h1 at k=32+j (j=0..99), pad 132..159
//  layer1, 7 kt (K=224): [ones k=0][pad 1..3][h1 k=4+j][h2 k=104+j][pad 204..223]
#define NKT 12
#define NMT 25
#define PER_NODE (NKT * NMT * 512)                  // 153,600 bf16 per node
#define WFRAG_ELEMS ((size_t)NN * PER_NODE)         // 19,353,600
#define XFRAG_ELEMS ((size_t)NN * TT * 4 * 64 * 8)  // 6,193,152
#define WS_NEEDED ((WFRAG_ELEMS + XFRAG_ELEMS) * 2) // 51,093,504 B

// LDS layout (bytes): L0 weights (5 kt) | X0 frags | X1 frags ; red overlays base in epilogue
#define ALDS_BYTES (5 * NMT * 1024)                 // 128,000
#define XF0_OFF ALDS_BYTES
#define XF1_OFF (XF0_OFF + 5 * 2 * 1024)            // +10,240
#define LDS_BYTES (XF1_OFF + 7 * 2 * 1024)          // 152,576

typedef __attribute__((ext_vector_type(8))) short short8v;
typedef __attribute__((ext_vector_type(4))) float float4v;

__device__ __forceinline__ short f2bf(float f) {
    union { float f; unsigned u; } v; v.f = f;
    unsigned r = v.u + 0x7FFFu + ((v.u >> 16) & 1u);   // RNE
    return (short)(r >> 16);
}
__device__ __forceinline__ float sigmf(float x) { return 1.0f / (1.0f + __expf(-x)); }
__device__ __forceinline__ float tanhf_(float x) { return 2.0f / (1.0f + __expf(-2.0f * x)) - 1.0f; }

// ---------------- prep: weights -> bf16 MFMA A-fragments ----------------
// wfrag[n][kt 0..11][mt 0..24][lane][e]
__global__ void prep_w(const float* __restrict__ Wih0, const float* __restrict__ Whh0,
                       const float* __restrict__ bih0, const float* __restrict__ bhh0,
                       const float* __restrict__ Wih1, const float* __restrict__ Whh1,
                       const float* __restrict__ bih1, const float* __restrict__ bhh1,
                       short* __restrict__ wfrag)
{
    const int idx = blockIdx.x * 256 + threadIdx.x;
    if (idx >= NN * NKT * NMT * 64) return;
    const int lane = idx & 63;
    int r = idx >> 6;
    const int mt = r % NMT; r /= NMT;
    const int kt = r % NKT;
    const int n  = r / NKT;

    const int row16 = lane & 15, kq = lane >> 4;
    const int gr = mt * 16 + row16;
    const int cell = gr >> 2, g = gr & 3;
    const int orow = n * 400 + g * HH + cell;   // gate blocks i,f,g,o

    short8v pv;
    #pragma unroll
    for (int e = 0; e < 8; ++e) {
        const int kk = kq * 8 + e;
        float f = 0.0f;
        if (kt == 0) {                          // L0: x + bias
            if (kk < FF)       f = Wih0[(size_t)orow * FF + kk];
            else if (kk == FF) f = bih0[orow] + bhh0[orow];
        } else if (kt < 5) {                    // L0: h1 (k = 32 + j)
            const int j = (kt - 1) * 32 + kk;
            if (j < HH) f = Whh0[(size_t)orow * HH + j];
        } else {                                // L1
            const int k = (kt - 5) * 32 + kk;
            if (k == 0)                       f = bih1[orow] + bhh1[orow];
            else if (k >= 4 && k < 4 + HH)    f = Wih1[(size_t)orow * HH + (k - 4)];
            else if (k >= 104 && k < 104+HH)  f = Whh1[(size_t)orow * HH + (k - 104)];
        }
        pv[e] = f2bf(f);
    }
    *(short8v*)(wfrag + (size_t)idx * 8) = pv;
}

// ---------------- prep: x -> bf16 B-fragments (kt0 of layer0) ----------------
// xfrag[n][t][bq 0..3][lane][e]; k = (lane>>4)*8+e: k<17 -> x, k==17 -> 1.0, else 0
__global__ void prep_x(const float* __restrict__ x, short* __restrict__ xfrag)
{
    const int idx = blockIdx.x * 256 + threadIdx.x;
    if (idx >= NN * TT * 4 * 64) return;
    const int lane = idx & 63;
    int r = idx >> 6;
    const int bq = r & 3; r >>= 2;
    const int t = r % TT;
    const int n = r / TT;
    const int b = bq * 16 + (lane & 15);
    const int kq = lane >> 4;

    short8v pv;
    #pragma unroll
    for (int e = 0; e < 8; ++e) {
        const int k = kq * 8 + e;
        float f = 0.0f;
        if (k < FF)       f = x[(((size_t)b * TT + t) * NN + n) * FF + k];
        else if (k == FF) f = 1.0f;
        pv[e] = f2bf(f);
    }
    *(short8v*)(xfrag + (size_t)idx * 8) = pv;
}

// ---------------- main: weight-resident MFMA LSTM ----------------
__global__ __launch_bounds__(512, 2)
void lstm_mfma2(const short* __restrict__ wfrag, const short* __restrict__ xfrag,
                const float* __restrict__ wlin, const float* __restrict__ blin,
                const float* __restrict__ wend, const float* __restrict__ bend,
                float* __restrict__ out)
{
    extern __shared__ char lds[];
    short* Al  = (short*)lds;                 // [5][25][64][8] L0 weights
    short* X0  = (short*)(lds + XF0_OFF);     // [5][2][64][8]
    short* X1  = (short*)(lds + XF1_OFF);     // [7][2][64][8]
    float* red = (float*)lds;                 // overlay, epilogue only

    const int n   = blockIdx.x >> 1;
    const int bh  = blockIdx.x & 1;           // batch half
    const int tid = threadIdx.x, lane = tid & 63, w = tid >> 6;
    const int cl  = lane & 15, q = lane >> 4;
    const int mt0 = w * 3;
    const int nmt = (w == 7) ? 4 : 3;         // wave 7 takes tile 24

    const short* wnode = wfrag + (size_t)n * PER_NODE;

    // ---- init: zero X frags, stage L0 weights to LDS, L1 weights to VGPRs ----
    {
        const short8v z = {0,0,0,0,0,0,0,0};
        for (int i = tid; i < (5 * 2 + 7 * 2) * 64; i += 512)   // X0+X1 contiguous
            *(short8v*)(X0 + (size_t)i * 8) = z;
    }
    for (int i = tid; i < 5 * NMT * 64; i += 512)
        *(short8v*)(Al + (size_t)i * 8) = *(const short8v*)(wnode + (size_t)i * 8);

    short8v wreg[4][7];                       // L1 weights, kt 5..11, this wave's tiles
    #pragma unroll
    for (int mi = 0; mi < 4; ++mi) {
        if (mi < nmt) {
            #pragma unroll
            for (int kt = 0; kt < 7; ++kt)
                wreg[mi][kt] = *(const short8v*)(
                    wnode + (((size_t)(5 + kt) * NMT + (mt0 + mi)) * 64 + lane) * 8);
        }
    }
    __syncthreads();
    // ones column for L1 bias (k=0 -> kq=0,e=0, cols 0..15, both nh)
    if (tid < 32) X1[(((tid >> 4)) * 64 + (tid & 15)) * 8 + 0] = (short)0x3F80;
    // x(t=0)
    if (w < 2)
        *(short8v*)(X0 + ((size_t)w * 64 + lane) * 8) =
            *(const short8v*)(xfrag + ((((size_t)n * TT + 0) * 4 + (bh * 2 + w)) * 64 + lane) * 8);
    __syncthreads();

    float c1[4][2], c2[4][2], macc[4][2];
    #pragma unroll
    for (int mi = 0; mi < 4; ++mi)
        #pragma unroll
        for (int nh = 0; nh < 2; ++nh) { c1[mi][nh] = 0.f; c2[mi][nh] = 0.f; macc[mi][nh] = 0.f; }

    for (int t = 0; t < TT; ++t) {
        float4v acc[4][2];
        #pragma unroll
        for (int mi = 0; mi < 4; ++mi) { acc[mi][0] = (float4v){0,0,0,0}; acc[mi][1] = (float4v){0,0,0,0}; }

        // -------- layer 0: A from LDS --------
        #pragma unroll
        for (int kt = 0; kt < 5; ++kt) {
            const short8v b0 = *(const short8v*)(X0 + (((size_t)kt * 2 + 0) * 64 + lane) * 8);
            const short8v b1 = *(const short8v*)(X0 + (((size_t)kt * 2 + 1) * 64 + lane) * 8);
            #pragma unroll
            for (int mi = 0; mi < 4; ++mi) {
                if (mi < nmt) {
                    const short8v a = *(const short8v*)(
                        Al + (((size_t)kt * NMT + (mt0 + mi)) * 64 + lane) * 8);
                    acc[mi][0] = __builtin_amdgcn_mfma_f32_16x16x32_bf16(a, b0, acc[mi][0], 0, 0, 0);
                    acc[mi][1] = __builtin_amdgcn_mfma_f32_16x16x32_bf16(a, b1, acc[mi][1], 0, 0, 0);
                }
            }
        }
        __syncthreads();   // A: X0 reads done

        // -------- layer 0 activation --------
        #pragma unroll
        for (int mi = 0; mi < 4; ++mi) {
            if (mi < nmt) {
                const int cell = (mt0 + mi) * 4 + q;
                #pragma unroll
                for (int nh = 0; nh < 2; ++nh) {
                    const float iv = sigmf(acc[mi][nh][0]);
                    const float fv = sigmf(acc[mi][nh][1]);
                    const float gv = tanhf_(acc[mi][nh][2]);
                    const float ov = sigmf(acc[mi][nh][3]);
                    const float c  = fv * c1[mi][nh] + iv * gv;
                    c1[mi][nh] = c;
                    const float h = ov * tanhf_(c);
                    const short hb = f2bf(h);
                    { const int k = 32 + cell;   // X0 kt 1..4
                      X0[(((size_t)(k >> 5) * 2 + nh) * 64 + ((((k >> 3) & 3) << 4) | cl)) * 8 + (k & 7)] = hb; }
                    { const int k = 4 + cell;    // X1 kt 0..3
                      X1[(((size_t)(k >> 5) * 2 + nh) * 64 + ((((k >> 3) & 3) << 4) | cl)) * 8 + (k & 7)] = hb; }
                    if (t == TT - 1) {
                        const int b = bh * 32 + nh * 16 + cl;
                        out[8064 + ((size_t)(n * 2 + 0) * 64 + b) * HH + cell] = h;
                        out[8064 + 1612800 + ((size_t)(n * 2 + 0) * 64 + b) * HH + cell] = c;
                    }
                }
            }
        }
        __syncthreads();   // B: h1 fragments visible

        // -------- layer 1: A from VGPRs --------
        #pragma unroll
        for (int mi = 0; mi < 4; ++mi) { acc[mi][0] = (float4v){0,0,0,0}; acc[mi][1] = (float4v){0,0,0,0}; }
        #pragma unroll
        for (int kt = 0; kt < 7; ++kt) {
            const short8v b0 = *(const short8v*)(X1 + (((size_t)kt * 2 + 0) * 64 + lane) * 8);
            const short8v b1 = *(const short8v*)(X1 + (((size_t)kt * 2 + 1) * 64 + lane) * 8);
            #pragma unroll
            for (int mi = 0; mi < 4; ++mi) {
                if (mi < nmt) {
                    acc[mi][0] = __builtin_amdgcn_mfma_f32_16x16x32_bf16(wreg[mi][kt], b0, acc[mi][0], 0, 0, 0);
                    acc[mi][1] = __builtin_amdgcn_mfma_f32_16x16x32_bf16(wreg[mi][kt], b1, acc[mi][1], 0, 0, 0);
                }
            }
        }
        __syncthreads();   // C: X1 reads done

        // -------- layer 1 activation + x(t+1) stage --------
        const float wet = wend[t];
        #pragma unroll
        for (int mi = 0; mi < 4; ++mi) {
            if (mi < nmt) {
                const int cell = (mt0 + mi) * 4 + q;
                #pragma unroll
                for (int nh = 0; nh < 2; ++nh) {
                    const float iv = sigmf(acc[mi][nh][0]);
                    const float fv = sigmf(acc[mi][nh][1]);
                    const float gv = tanhf_(acc[mi][nh][2]);
                    const float ov = sigmf(acc[mi][nh][3]);
                    const float c  = fv * c2[mi][nh] + iv * gv;
                    c2[mi][nh] = c;
                    const float h = ov * tanhf_(c);
                    macc[mi][nh] = fmaf(wet, h, macc[mi][nh]);
                    { const int k = 104 + cell;  // X1 kt 3..6
                      X1[(((size_t)(k >> 5) * 2 + nh) * 64 + ((((k >> 3) & 3) << 4) | cl)) * 8 + (k & 7)] = f2bf(h); }
                    if (t == TT - 1) {
                        const int b = bh * 32 + nh * 16 + cl;
                        out[8064 + ((size_t)(n * 2 + 1) * 64 + b) * HH + cell] = h;
                        out[8064 + 1612800 + ((size_t)(n * 2 + 1) * 64 + b) * HH + cell] = c;
                    }
                }
            }
        }
        if (w < 2 && t + 1 < TT)
            *(short8v*)(X0 + ((size_t)w * 64 + lane) * 8) =
                *(const short8v*)(xfrag + ((((size_t)n * TT + (t + 1)) * 4 + (bh * 2 + w)) * 64 + lane) * 8);
        __syncthreads();   // D: h2 / x visible for next step
    }

    // -------- epilogue: out[b,0,n,0] (red overlays Al) --------
    #pragma unroll
    for (int mi = 0; mi < 4; ++mi) {
        if (mi < nmt) {
            const int cell = (mt0 + mi) * 4 + q;
            #pragma unroll
            for (int nh = 0; nh < 2; ++nh)
                red[cell * 32 + nh * 16 + cl] = wlin[cell] * macc[mi][nh];
        }
    }
    __syncthreads();
    if (tid < 32) {
        float s = 0.0f;
        for (int j = 0; j < HH; ++j) s += red[j * 32 + tid];
        float ws = 0.0f;
        for (int t2 = 0; t2 < TT; ++t2) ws += wend[t2];
        s += blin[0] * ws + bend[0];
        out[(size_t)(bh * 32 + tid) * NN + n] = s;
    }
}

// ================= fallback (R1 fp32 kernel, known-good) =================
#define BH 32
#define BPG 8
#define NTH 448

__global__ __launch_bounds__(NTH, 1)
void lstm_fused(const float* __restrict__ x,
                const float* __restrict__ Wih0, const float* __restrict__ Whh0,
                const float* __restrict__ bih0, const float* __restrict__ bhh0,
                const float* __restrict__ Wih1, const float* __restrict__ Whh1,
                const float* __restrict__ bih1, const float* __restrict__ bhh1,
                const float* __restrict__ wlin, const float* __restrict__ blin,
                const float* __restrict__ wend, const float* __restrict__ bend,
                float* __restrict__ out)
{
    const int n   = blockIdx.x >> 1;
    const int b0  = (blockIdx.x & 1) * BH;
    const int tid = threadIdx.x;
    const int j   = tid >> 2;
    const int bg  = tid & 3;
    const int bl0 = bg * BPG;
    const bool act = (j < HH);

    __shared__ float h1t[HH][BH];
    __shared__ float h2t[HH][BH];
    __shared__ float xt[FF][BH];
    __shared__ float red[HH][BH];

    for (int idx = tid; idx < HH * BH; idx += NTH) {
        (&h1t[0][0])[idx] = 0.0f;
        (&h2t[0][0])[idx] = 0.0f;
    }
    float c1[BPG], c2[BPG], macc[BPG];
    #pragma unroll
    for (int q = 0; q < BPG; ++q) { c1[q] = 0.0f; c2[q] = 0.0f; macc[q] = 0.0f; }

    float bs0[4], bs1[4];
    const float* wx0r[4];
    const float* w0r[4];
    const float* wi1r[4];
    const float* w1r[4];
    if (act) {
        #pragma unroll
        for (int g = 0; g < 4; ++g) {
            const int row = n * 400 + g * HH + j;
            bs0[g] = bih0[row] + bhh0[row];
            bs1[g] = bih1[row] + bhh1[row];
            wx0r[g] = Wih0 + (size_t)row * FF;
            w0r[g]  = Whh0 + (size_t)row * HH;
            wi1r[g] = Wih1 + (size_t)row * HH;
            w1r[g]  = Whh1 + (size_t)row * HH;
        }
    }
    __syncthreads();

    for (int t = 0; t < TT; ++t) {
        for (int idx = tid; idx < FF * BH; idx += NTH) {
            const int f = idx >> 5, bl = idx & 31;
            xt[f][bl] = x[(((b0 + bl) * TT + t) * NN + n) * FF + f];
        }
        __syncthreads();

        float ga[4][BPG];
        if (act) {
            #pragma unroll
            for (int g = 0; g < 4; ++g)
                #pragma unroll
                for (int q = 0; q < BPG; ++q) ga[g][q] = bs0[g];
            for (int f = 0; f < FF; ++f) {
                float wv[4];
                #pragma unroll
                for (int g = 0; g < 4; ++g) wv[g] = wx0r[g][f];
                #pragma unroll
                for (int q = 0; q < BPG; ++q) {
                    const float xv = xt[f][bl0 + q];
                    #pragma unroll
                    for (int g = 0; g < 4; ++g) ga[g][q] = fmaf(wv[g], xv, ga[g][q]);
                }
            }
            for (int k = 0; k < HH; k += 4) {
                float wg[4][4];
                #pragma unroll
                for (int g = 0; g < 4; ++g) {
                    const float4 wv = *(const float4*)(w0r[g] + k);
                    wg[g][0] = wv.x; wg[g][1] = wv.y; wg[g][2] = wv.z; wg[g][3] = wv.w;
                }
                #pragma unroll
                for (int kk = 0; kk < 4; ++kk) {
                    const float4* hr = (const float4*)(&h1t[k + kk][bl0]);
                    const float4 ha = hr[0], hb2 = hr[1];
                    const float hv[BPG] = {ha.x, ha.y, ha.z, ha.w, hb2.x, hb2.y, hb2.z, hb2.w};
                    #pragma unroll
                    for (int q = 0; q < BPG; ++q)
                        #pragma unroll
                        for (int g = 0; g < 4; ++g)
                            ga[g][q] = fmaf(wg[g][kk], hv[q], ga[g][q]);
                }
            }
        }
        __syncthreads();
        if (act) {
            #pragma unroll
            for (int q = 0; q < BPG; ++q) {
                const float iv = sigmf(ga[0][q]);
                const float fv = sigmf(ga[1][q]);
                const float gv = tanhf_(ga[2][q]);
                const float ov = sigmf(ga[3][q]);
                const float c  = fv * c1[q] + iv * gv;
                c1[q] = c;
                h1t[j][bl0 + q] = ov * tanhf_(c);
            }
        }
        __syncthreads();
        if (act) {
            #pragma unroll
            for (int g = 0; g < 4; ++g)
                #pragma unroll
                for (int q = 0; q < BPG; ++q) ga[g][q] = bs1[g];
            for (int k = 0; k < HH; k += 4) {
                float wg[4][4];
                #pragma unroll
                for (int g = 0; g < 4; ++g) {
                    const float4 wv = *(const float4*)(wi1r[g] + k);
                    wg[g][0] = wv.x; wg[g][1] = wv.y; wg[g][2] = wv.z; wg[g][3] = wv.w;
                }
                #pragma unroll
                for (int kk = 0; kk < 4; ++kk) {
                    const float4* hr = (const float4*)(&h1t[k + kk][bl0]);
                    const float4 ha = hr[0], hb2 = hr[1];
                    const float hv[BPG] = {ha.x, ha.y, ha.z, ha.w, hb2.x, hb2.y, hb2.z, hb2.w};
                    #pragma unroll
                    for (int q = 0; q < BPG; ++q)
                        #pragma unroll
                        for (int g = 0; g < 4; ++g)
                            ga[g][q] = fmaf(wg[g][kk], hv[q], ga[g][q]);
                }
            }
            for (int k = 0; k < HH; k += 4) {
                float wg[4][4];
                #pragma unroll
                for (int g = 0; g < 4; ++g) {
                    const float4 wv = *(const float4*)(w1r[g] + k);
                    wg[g][0] = wv.x; wg[g][1] = wv.y; wg[g][2] = wv.z; wg[g][3] = wv.w;
                }
                #pragma unroll
                for (int kk = 0; kk < 4; ++kk) {
                    const float4* hr = (const float4*)(&h2t[k + kk][bl0]);
                    const float4 ha = hr[0], hb2 = hr[1];
                    const float hv[BPG] = {ha.x, ha.y, ha.z, ha.w, hb2.x, hb2.y, hb2.z, hb2.w};
                    #pragma unroll
                    for (int q = 0; q < BPG; ++q)
                        #pragma unroll
                        for (int g = 0; g < 4; ++g)
                            ga[g][q] = fmaf(wg[g][kk], hv[q], ga[g][q]);
                }
            }
        }
        __syncthreads();
        const float wet = wend[t];
        if (act) {
            #pragma unroll
            for (int q = 0; q < BPG; ++q) {
                const float iv = sigmf(ga[0][q]);
                const float fv = sigmf(ga[1][q]);
                const float gv = tanhf_(ga[2][q]);
                const float ov = sigmf(ga[3][q]);
                const float c  = fv * c2[q] + iv * gv;
                c2[q] = c;
                const float h = ov * tanhf_(c);
                h2t[j][bl0 + q] = h;
                macc[q] = fmaf(wet, h, macc[q]);
            }
        }
    }

    if (act) {
        #pragma unroll
        for (int q = 0; q < BPG; ++q) {
            const int b = b0 + bl0 + q;
            const size_t hbase = 8064 + (size_t)n * 12800 + (size_t)b * HH + j;
            out[hbase]                  = h1t[j][bl0 + q];
            out[hbase + 6400]           = h2t[j][bl0 + q];
            out[hbase + 1612800]        = c1[q];
            out[hbase + 6400 + 1612800] = c2[q];
            red[j][bl0 + q] = wlin[j] * macc[q];
        }
    }
    __syncthreads();
    if (tid < BH) {
        float s = 0.0f;
        for (int jj = 0; jj < HH; ++jj) s += red[jj][tid];
        float ws = 0.0f;
        for (int t2 = 0; t2 < TT; ++t2) ws += wend[t2];
        s += blin[0] * ws + bend[0];
        out[(size_t)(b0 + tid) * NN + n] = s;
    }
}

extern "C" void kernel_launch(void* const* d_in, const int* in_sizes, int n_in,
                              void* d_out, int out_size, void* d_ws, size_t ws_size,
                              hipStream_t stream) {
    const float* x    = (const float*)d_in[0];
    const float* Wih0 = (const float*)d_in[1];
    const float* Whh0 = (const float*)d_in[2];
    const float* bih0 = (const float*)d_in[3];
    const float* bhh0 = (const float*)d_in[4];
    const float* Wih1 = (const float*)d_in[5];
    const float* Whh1 = (const float*)d_in[6];
    const float* bih1 = (const float*)d_in[7];
    const float* bhh1 = (const float*)d_in[8];
    const float* wlin = (const float*)d_in[9];
    const float* blin = (const float*)d_in[10];
    const float* wend = (const float*)d_in[11];
    const float* bend = (const float*)d_in[12];

    if (ws_size < WS_NEEDED) {
        lstm_fused<<<dim3(NN * 2), dim3(NTH), 0, stream>>>(
            x, Wih0, Whh0, bih0, bhh0, Wih1, Whh1, bih1, bhh1,
            wlin, blin, wend, bend, (float*)d_out);
        return;
    }

    short* wfrag = (short*)d_ws;
    short* xfrag = wfrag + WFRAG_ELEMS;

    prep_w<<<dim3((NN * NKT * NMT * 64 + 255) / 256), dim3(256), 0, stream>>>(
        Wih0, Whh0, bih0, bhh0, Wih1, Whh1, bih1, bhh1, wfrag);
    prep_x<<<dim3((NN * TT * 4 * 64 + 255) / 256), dim3(256), 0, stream>>>(x, xfrag);
    lstm_mfma2<<<dim3(NN * 2), dim3(512), LDS_BYTES, stream>>>(
        wfrag, xfrag, wlin, blin, wend, bend, (float*)d_out);
}

// Round 5
// 143.154 us; speedup vs baseline: 7.7332x; 1.5803x over previous
//
#include <hip/hip_runtime.h>
#include <hip/hip_bf16.h>

#define NN 126   // nodes
#define TT 24    // seq len
#define FF 17    // input feat
#define HH 100   // hidden

// ---------- MFMA fragment geometry (R3-derived, L0 packed to 4 kt) ----------
// M: gate rows interleaved gr = cell*4 + gate -> 400 rows = exactly 25 tiles of 16.
//  L0, kt 0..3  (K=128): k<17 x | k==17 bias | k=18+j h1(j<100) | pad 118..127
//  L1, kt 4..10 (K=224): k==0 ones(bias) | pad 1..3 | k=4+j h1 | k=104+j h2 | pad 204..223
#define NKT 11
#define NMT 25
#define PER_NODE (NKT * NMT * 512)                  // 140,800 bf16 per node
#define WFRAG_ELEMS ((size_t)NN * PER_NODE)         // 17,740,800
#define XFRAG_ELEMS ((size_t)NN * TT * 4 * 64 * 8)  // 6,193,152
#define WS_NEEDED ((WFRAG_ELEMS + XFRAG_ELEMS) * 2) // 47,867,904 B

// LDS (bytes): L0 weights (4 kt) | X0 (4 kt) | X1 (7 kt); red overlays base in epilogue
#define ALDS_BYTES (4 * NMT * 1024)                 // 102,400
#define XF0_OFF ALDS_BYTES
#define XF1_OFF (XF0_OFF + 4 * 2 * 1024)            // 110,592
#define LDS_BYTES (XF1_OFF + 7 * 2 * 1024)          // 124,928

typedef __attribute__((ext_vector_type(8))) short short8v;
typedef __attribute__((ext_vector_type(4))) float float4v;

__device__ __forceinline__ short f2bf(float f) {
    union { float f; unsigned u; } v; v.f = f;
    unsigned r = v.u + 0x7FFFu + ((v.u >> 16) & 1u);   // RNE
    return (short)(r >> 16);
}
#define LOG2E 1.4426950408889634f
__device__ __forceinline__ float sigm_(float x) {
    return __builtin_amdgcn_rcpf(1.0f + __builtin_amdgcn_exp2f(-LOG2E * x));
}
__device__ __forceinline__ float tanh_(float x) {
    return 1.0f - 2.0f * __builtin_amdgcn_rcpf(1.0f + __builtin_amdgcn_exp2f((2.0f * LOG2E) * x));
}
// exact versions for the fallback kernel
__device__ __forceinline__ float sigmf(float x) { return 1.0f / (1.0f + __expf(-x)); }
__device__ __forceinline__ float tanhf_(float x) { return 2.0f / (1.0f + __expf(-2.0f * x)) - 1.0f; }

// ---------------- prep: weights -> bf16 MFMA A-fragments ----------------
// wfrag[n][kt 0..10][mt 0..24][lane][e]
__global__ void prep_w(const float* __restrict__ Wih0, const float* __restrict__ Whh0,
                       const float* __restrict__ bih0, const float* __restrict__ bhh0,
                       const float* __restrict__ Wih1, const float* __restrict__ Whh1,
                       const float* __restrict__ bih1, const float* __restrict__ bhh1,
                       short* __restrict__ wfrag)
{
    const int idx = blockIdx.x * 256 + threadIdx.x;
    if (idx >= NN * NKT * NMT * 64) return;
    const int lane = idx & 63;
    int r = idx >> 6;
    const int mt = r % NMT; r /= NMT;
    const int kt = r % NKT;
    const int n  = r / NKT;

    const int row16 = lane & 15, kq = lane >> 4;
    const int gr = mt * 16 + row16;
    const int cell = gr >> 2, g = gr & 3;
    const int orow = n * 400 + g * HH + cell;   // gate blocks i,f,g,o

    short8v pv;
    #pragma unroll
    for (int e = 0; e < 8; ++e) {
        const int kk = kq * 8 + e;
        float f = 0.0f;
        if (kt < 4) {                           // L0 packed
            const int k = kt * 32 + kk;
            if (k < FF)        f = Wih0[(size_t)orow * FF + k];
            else if (k == FF)  f = bih0[orow] + bhh0[orow];
            else { const int j = k - 18; if (j < HH) f = Whh0[(size_t)orow * HH + j]; }
        } else {                                // L1
            const int k = (kt - 4) * 32 + kk;
            if (k == 0)                       f = bih1[orow] + bhh1[orow];
            else if (k >= 4 && k < 4 + HH)    f = Wih1[(size_t)orow * HH + (k - 4)];
            else if (k >= 104 && k < 104+HH)  f = Whh1[(size_t)orow * HH + (k - 104)];
        }
        pv[e] = f2bf(f);
    }
    *(short8v*)(wfrag + (size_t)idx * 8) = pv;
}

// ---------------- prep: x -> bf16 B-fragments ----------------
// xfrag[n][t][bq 0..3][lane][e]; k = (lane>>4)*8+e: k<17 -> x, k==17 -> 1.0, else 0
__global__ void prep_x(const float* __restrict__ x, short* __restrict__ xfrag)
{
    const int idx = blockIdx.x * 256 + threadIdx.x;
    if (idx >= NN * TT * 4 * 64) return;
    const int lane = idx & 63;
    int r = idx >> 6;
    const int bq = r & 3; r >>= 2;
    const int t = r % TT;
    const int n = r / TT;
    const int b = bq * 16 + (lane & 15);
    const int kq = lane >> 4;

    short8v pv;
    #pragma unroll
    for (int e = 0; e < 8; ++e) {
        const int k = kq * 8 + e;
        float f = 0.0f;
        if (k < FF)       f = x[(((size_t)b * TT + t) * NN + n) * FF + k];
        else if (k == FF) f = 1.0f;
        pv[e] = f2bf(f);
    }
    *(short8v*)(xfrag + (size_t)idx * 8) = pv;
}

// ---------------- main: 16-wave weight-resident MFMA LSTM (R3 4-barrier schedule) ----------------
__global__ __launch_bounds__(1024, 4)
void lstm_mfma4(const short* __restrict__ wfrag, const short* __restrict__ xfrag,
                const float* __restrict__ wlin, const float* __restrict__ blin,
                const float* __restrict__ wend, const float* __restrict__ bend,
                float* __restrict__ out)
{
    extern __shared__ char lds[];
    short* Al  = (short*)lds;                 // [4][25][64][8] L0 weights
    short* X0  = (short*)(lds + XF0_OFF);     // [4][2][64][8]
    short* X1  = (short*)(lds + XF1_OFF);     // [7][2][64][8]
    float* red = (float*)lds;                 // overlay, epilogue only

    const int n   = blockIdx.x >> 1;
    const int bh  = blockIdx.x & 1;           // batch half (32 each)
    const int tid = threadIdx.x, lane = tid & 63, w = tid >> 6;   // 16 waves
    const int cl  = lane & 15, q = lane >> 4;
    const int mt0 = (w <= 8) ? (w * 2) : (18 + (w - 9));   // waves 0..8: 2 tiles; 9..15: 1 tile
    const int nmt = (w <= 8) ? 2 : 1;

    const short* wnode = wfrag + (size_t)n * PER_NODE;

    // ---- init: zero X frags, stage L0 weights -> LDS, L1 weights -> regs ----
    {
        const short8v z = {0,0,0,0,0,0,0,0};
        for (int i = tid; i < (4 * 2 + 7 * 2) * 64; i += 1024)   // X0+X1 contiguous
            *(short8v*)(X0 + (size_t)i * 8) = z;
    }
    for (int i = tid; i < 4 * NMT * 64; i += 1024)
        *(short8v*)(Al + (size_t)i * 8) = *(const short8v*)(wnode + (size_t)i * 8);

    short8v wreg[2][7];                       // L1 weights, kt 4..10, this wave's tiles
    #pragma unroll
    for (int mi = 0; mi < 2; ++mi) {
        if (mi < nmt) {
            #pragma unroll
            for (int kt = 0; kt < 7; ++kt)
                wreg[mi][kt] = *(const short8v*)(
                    wnode + (((size_t)(4 + kt) * NMT + (mt0 + mi)) * 64 + lane) * 8);
        }
    }
    __syncthreads();
    // ones column for L1 bias (k=0 -> kq=0,e=0, cols 0..15, both nh)
    if (tid < 32) X1[(((tid >> 4)) * 64 + (tid & 15)) * 8 + 0] = (short)0x3F80;

    // x staging writes ONLY k=0..17 of X0 kt0 (k>=18 holds packed h1)
    auto stage_x = [&](int t) {
        if (t < TT && w < 2) {
            const short8v v = *(const short8v*)(
                xfrag + ((((size_t)n * TT + t) * 4 + (bh * 2 + w)) * 64 + lane) * 8);
            if (q < 2)       *(short8v*)(X0 + ((size_t)w * 64 + lane) * 8) = v;        // k 0..15
            else if (q == 2) *(int*)(X0 + ((size_t)w * 64 + lane) * 8) = *(const int*)&v; // k 16,17
        }
    };
    stage_x(0);
    __syncthreads();

    float c1[2][2], c2[2][2], macc[2][2];
    #pragma unroll
    for (int mi = 0; mi < 2; ++mi)
        #pragma unroll
        for (int nh = 0; nh < 2; ++nh) { c1[mi][nh] = 0.f; c2[mi][nh] = 0.f; macc[mi][nh] = 0.f; }

    for (int t = 0; t < TT; ++t) {
        const bool fin = (t == TT - 1);
        float4v acc[2][2];

        // -------- layer 0 MFMA: A from LDS, 4 kt --------
        #pragma unroll
        for (int mi = 0; mi < 2; ++mi) { acc[mi][0] = (float4v){0,0,0,0}; acc[mi][1] = (float4v){0,0,0,0}; }
        #pragma unroll
        for (int kt = 0; kt < 4; ++kt) {
            const short8v b0 = *(const short8v*)(X0 + (((size_t)kt * 2 + 0) * 64 + lane) * 8);
            const short8v b1 = *(const short8v*)(X0 + (((size_t)kt * 2 + 1) * 64 + lane) * 8);
            #pragma unroll
            for (int mi = 0; mi < 2; ++mi) {
                if (mi < nmt) {
                    const short8v a = *(const short8v*)(
                        Al + (((size_t)kt * NMT + (mt0 + mi)) * 64 + lane) * 8);
                    acc[mi][0] = __builtin_amdgcn_mfma_f32_16x16x32_bf16(a, b0, acc[mi][0], 0, 0, 0);
                    acc[mi][1] = __builtin_amdgcn_mfma_f32_16x16x32_bf16(a, b1, acc[mi][1], 0, 0, 0);
                }
            }
        }
        __syncthreads();   // A: X0 reads done

        // -------- layer 0 activation: h1(t) --------
        #pragma unroll
        for (int mi = 0; mi < 2; ++mi) {
            if (mi < nmt) {
                const int cell = (mt0 + mi) * 4 + q;
                #pragma unroll
                for (int nh = 0; nh < 2; ++nh) {
                    const float iv = sigm_(acc[mi][nh][0]);
                    const float fv = sigm_(acc[mi][nh][1]);
                    const float gv = tanh_(acc[mi][nh][2]);
                    const float ov = sigm_(acc[mi][nh][3]);
                    const float c  = fv * c1[mi][nh] + iv * gv;
                    c1[mi][nh] = c;
                    const float h = ov * tanh_(c);
                    const short hb = f2bf(h);
                    { const int k = 18 + cell;   // X0 packed h1
                      X0[(((k >> 5) * 2 + nh) * 64 + ((((k >> 3) & 3) << 4) | cl)) * 8 + (k & 7)] = hb; }
                    { const int k = 4 + cell;    // X1 h1
                      X1[(((k >> 5) * 2 + nh) * 64 + ((((k >> 3) & 3) << 4) | cl)) * 8 + (k & 7)] = hb; }
                    if (fin) {
                        const int b = bh * 32 + nh * 16 + cl;
                        out[8064 + ((size_t)(n * 2 + 0) * 64 + b) * HH + cell] = h;
                        out[8064 + 1612800 + ((size_t)(n * 2 + 0) * 64 + b) * HH + cell] = c;
                    }
                }
            }
        }
        __syncthreads();   // B: h1 fragments visible

        // -------- layer 1 MFMA: A from VGPRs, 7 kt --------
        #pragma unroll
        for (int mi = 0; mi < 2; ++mi) { acc[mi][0] = (float4v){0,0,0,0}; acc[mi][1] = (float4v){0,0,0,0}; }
        #pragma unroll
        for (int kt = 0; kt < 7; ++kt) {
            const short8v b0 = *(const short8v*)(X1 + (((size_t)kt * 2 + 0) * 64 + lane) * 8);
            const short8v b1 = *(const short8v*)(X1 + (((size_t)kt * 2 + 1) * 64 + lane) * 8);
            #pragma unroll
            for (int mi = 0; mi < 2; ++mi) {
                if (mi < nmt) {
                    acc[mi][0] = __builtin_amdgcn_mfma_f32_16x16x32_bf16(wreg[mi][kt], b0, acc[mi][0], 0, 0, 0);
                    acc[mi][1] = __builtin_amdgcn_mfma_f32_16x16x32_bf16(wreg[mi][kt], b1, acc[mi][1], 0, 0, 0);
                }
            }
        }
        __syncthreads();   // C: X1 reads done

        // -------- layer 1 activation: h2(t); stage x(t+1) --------
        const float wet = wend[t];
        #pragma unroll
        for (int mi = 0; mi < 2; ++mi) {
            if (mi < nmt) {
                const int cell = (mt0 + mi) * 4 + q;
                #pragma unroll
                for (int nh = 0; nh < 2; ++nh) {
                    const float iv = sigm_(acc[mi][nh][0]);
                    const float fv = sigm_(acc[mi][nh][1]);
                    const float gv = tanh_(acc[mi][nh][2]);
                    const float ov = sigm_(acc[mi][nh][3]);
                    const float c  = fv * c2[mi][nh] + iv * gv;
                    c2[mi][nh] = c;
                    const float h = ov * tanh_(c);
                    macc[mi][nh] = fmaf(wet, h, macc[mi][nh]);
                    if (!fin) { const int k = 104 + cell;  // X1 h2
                      X1[(((k >> 5) * 2 + nh) * 64 + ((((k >> 3) & 3) << 4) | cl)) * 8 + (k & 7)] = f2bf(h); }
                    if (fin) {
                        const int b = bh * 32 + nh * 16 + cl;
                        out[8064 + ((size_t)(n * 2 + 1) * 64 + b) * HH + cell] = h;
                        out[8064 + 1612800 + ((size_t)(n * 2 + 1) * 64 + b) * HH + cell] = c;
                    }
                }
            }
        }
        stage_x(t + 1);
        __syncthreads();   // D: h2 / x visible for next step
    }

    // -------- epilogue: out[b,0,n,0] (red overlays Al) --------
    #pragma unroll
    for (int mi = 0; mi < 2; ++mi) {
        if (mi < nmt) {
            const int cell = (mt0 + mi) * 4 + q;
            #pragma unroll
            for (int nh = 0; nh < 2; ++nh)
                red[cell * 32 + nh * 16 + cl] = wlin[cell] * macc[mi][nh];
        }
    }
    __syncthreads();
    if (tid < 32) {
        float s = 0.0f;
        for (int j = 0; j < HH; ++j) s += red[j * 32 + tid];
        float ws = 0.0f;
        for (int t2 = 0; t2 < TT; ++t2) ws += wend[t2];
        s += blin[0] * ws + bend[0];
        out[(size_t)(bh * 32 + tid) * NN + n] = s;
    }
}

// ================= fallback (R1 fp32 kernel, known-good) =================
#define BH 32
#define BPG 8
#define NTH 448

__global__ __launch_bounds__(NTH, 1)
void lstm_fused(const float* __restrict__ x,
                const float* __restrict__ Wih0, const float* __restrict__ Whh0,
                const float* __restrict__ bih0, const float* __restrict__ bhh0,
                const float* __restrict__ Wih1, const float* __restrict__ Whh1,
                const float* __restrict__ bih1, const float* __restrict__ bhh1,
                const float* __restrict__ wlin, const float* __restrict__ blin,
                const float* __restrict__ wend, const float* __restrict__ bend,
                float* __restrict__ out)
{
    const int n   = blockIdx.x >> 1;
    const int b0  = (blockIdx.x & 1) * BH;
    const int tid = threadIdx.x;
    const int j   = tid >> 2;
    const int bg  = tid & 3;
    const int bl0 = bg * BPG;
    const bool act = (j < HH);

    __shared__ float h1t[HH][BH];
    __shared__ float h2t[HH][BH];
    __shared__ float xt[FF][BH];
    __shared__ float red[HH][BH];

    for (int idx = tid; idx < HH * BH; idx += NTH) {
        (&h1t[0][0])[idx] = 0.0f;
        (&h2t[0][0])[idx] = 0.0f;
    }
    float c1[BPG], c2[BPG], macc[BPG];
    #pragma unroll
    for (int q = 0; q < BPG; ++q) { c1[q] = 0.0f; c2[q] = 0.0f; macc[q] = 0.0f; }

    float bs0[4], bs1[4];
    const float* wx0r[4];
    const float* w0r[4];
    const float* wi1r[4];
    const float* w1r[4];
    if (act) {
        #pragma unroll
        for (int g = 0; g < 4; ++g) {
            const int row = n * 400 + g * HH + j;
            bs0[g] = bih0[row] + bhh0[row];
            bs1[g] = bih1[row] + bhh1[row];
            wx0r[g] = Wih0 + (size_t)row * FF;
            w0r[g]  = Whh0 + (size_t)row * HH;
            wi1r[g] = Wih1 + (size_t)row * HH;
            w1r[g]  = Whh1 + (size_t)row * HH;
        }
    }
    __syncthreads();

    for (int t = 0; t < TT; ++t) {
        for (int idx = tid; idx < FF * BH; idx += NTH) {
            const int f = idx >> 5, bl = idx & 31;
            xt[f][bl] = x[(((b0 + bl) * TT + t) * NN + n) * FF + f];
        }
        __syncthreads();

        float ga[4][BPG];
        if (act) {
            #pragma unroll
            for (int g = 0; g < 4; ++g)
                #pragma unroll
                for (int q = 0; q < BPG; ++q) ga[g][q] = bs0[g];
            for (int f = 0; f < FF; ++f) {
                float wv[4];
                #pragma unroll
                for (int g = 0; g < 4; ++g) wv[g] = wx0r[g][f];
                #pragma unroll
                for (int q = 0; q < BPG; ++q) {
                    const float xv = xt[f][bl0 + q];
                    #pragma unroll
                    for (int g = 0; g < 4; ++g) ga[g][q] = fmaf(wv[g], xv, ga[g][q]);
                }
            }
            for (int k = 0; k < HH; k += 4) {
                float wg[4][4];
                #pragma unroll
                for (int g = 0; g < 4; ++g) {
                    const float4 wv = *(const float4*)(w0r[g] + k);
                    wg[g][0] = wv.x; wg[g][1] = wv.y; wg[g][2] = wv.z; wg[g][3] = wv.w;
                }
                #pragma unroll
                for (int kk = 0; kk < 4; ++kk) {
                    const float4* hr = (const float4*)(&h1t[k + kk][bl0]);
                    const float4 ha = hr[0], hb2 = hr[1];
                    const float hv[BPG] = {ha.x, ha.y, ha.z, ha.w, hb2.x, hb2.y, hb2.z, hb2.w};
                    #pragma unroll
                    for (int q = 0; q < BPG; ++q)
                        #pragma unroll
                        for (int g = 0; g < 4; ++g)
                            ga[g][q] = fmaf(wg[g][kk], hv[q], ga[g][q]);
                }
            }
        }
        __syncthreads();
        if (act) {
            #pragma unroll
            for (int q = 0; q < BPG; ++q) {
                const float iv = sigmf(ga[0][q]);
                const float fv = sigmf(ga[1][q]);
                const float gv = tanhf_(ga[2][q]);
                const float ov = sigmf(ga[3][q]);
                const float c  = fv * c1[q] + iv * gv;
                c1[q] = c;
                h1t[j][bl0 + q] = ov * tanhf_(c);
            }
        }
        __syncthreads();
        if (act) {
            #pragma unroll
            for (int g = 0; g < 4; ++g)
                #pragma unroll
                for (int q = 0; q < BPG; ++q) ga[g][q] = bs1[g];
            for (int k = 0; k < HH; k += 4) {
                float wg[4][4];
                #pragma unroll
                for (int g = 0; g < 4; ++g) {
                    const float4 wv = *(const float4*)(wi1r[g] + k);
                    wg[g][0] = wv.x; wg[g][1] = wv.y; wg[g][2] = wv.z; wg[g][3] = wv.w;
                }
                #pragma unroll
                for (int kk = 0; kk < 4; ++kk) {
                    const float4* hr = (const float4*)(&h1t[k + kk][bl0]);
                    const float4 ha = hr[0], hb2 = hr[1];
                    const float hv[BPG] = {ha.x, ha.y, ha.z, ha.w, hb2.x, hb2.y, hb2.z, hb2.w};
                    #pragma unroll
                    for (int q = 0; q < BPG; ++q)
                        #pragma unroll
                        for (int g = 0; g < 4; ++g)
                            ga[g][q] = fmaf(wg[g][kk], hv[q], ga[g][q]);
                }
            }
            for (int k = 0; k < HH; k += 4) {
                float wg[4][4];
                #pragma unroll
                for (int g = 0; g < 4; ++g) {
                    const float4 wv = *(const float4*)(w1r[g] + k);
                    wg[g][0] = wv.x; wg[g][1] = wv.y; wg[g][2] = wv.z; wg[g][3] = wv.w;
                }
                #pragma unroll
                for (int kk = 0; kk < 4; ++kk) {
                    const float4* hr = (const float4*)(&h2t[k + kk][bl0]);
                    const float4 ha = hr[0], hb2 = hr[1];
                    const float hv[BPG] = {ha.x, ha.y, ha.z, ha.w, hb2.x, hb2.y, hb2.z, hb2.w};
                    #pragma unroll
                    for (int q = 0; q < BPG; ++q)
                        #pragma unroll
                        for (int g = 0; g < 4; ++g)
                            ga[g][q] = fmaf(wg[g][kk], hv[q], ga[g][q]);
                }
            }
        }
        __syncthreads();
        const float wet = wend[t];
        if (act) {
            #pragma unroll
            for (int q = 0; q < BPG; ++q) {
                const float iv = sigmf(ga[0][q]);
                const float fv = sigmf(ga[1][q]);
                const float gv = tanhf_(ga[2][q]);
                const float ov = sigmf(ga[3][q]);
                const float c  = fv * c2[q] + iv * gv;
                c2[q] = c;
                const float h = ov * tanhf_(c);
                h2t[j][bl0 + q] = h;
                macc[q] = fmaf(wet, h, macc[q]);
            }
        }
    }

    if (act) {
        #pragma unroll
        for (int q = 0; q < BPG; ++q) {
            const int b = b0 + bl0 + q;
            const size_t hbase = 8064 + (size_t)n * 12800 + (size_t)b * HH + j;
            out[hbase]                  = h1t[j][bl0 + q];
            out[hbase + 6400]           = h2t[j][bl0 + q];
            out[hbase + 1612800]        = c1[q];
            out[hbase + 6400 + 1612800] = c2[q];
            red[j][bl0 + q] = wlin[j] * macc[q];
        }
    }
    __syncthreads();
    if (tid < BH) {
        float s = 0.0f;
        for (int jj = 0; jj < HH; ++jj) s += red[jj][tid];
        float ws = 0.0f;
        for (int t2 = 0; t2 < TT; ++t2) ws += wend[t2];
        s += blin[0] * ws + bend[0];
        out[(size_t)(b0 + tid) * NN + n] = s;
    }
}

extern "C" void kernel_launch(void* const* d_in, const int* in_sizes, int n_in,
                              void* d_out, int out_size, void* d_ws, size_t ws_size,
                              hipStream_t stream) {
    const float* x    = (const float*)d_in[0];
    const float* Wih0 = (const float*)d_in[1];
    const float* Whh0 = (const float*)d_in[2];
    const float* bih0 = (const float*)d_in[3];
    const float* bhh0 = (const float*)d_in[4];
    const float* Wih1 = (const float*)d_in[5];
    const float* Whh1 = (const float*)d_in[6];
    const float* bih1 = (const float*)d_in[7];
    const float* bhh1 = (const float*)d_in[8];
    const float* wlin = (const float*)d_in[9];
    const float* blin = (const float*)d_in[10];
    const float* wend = (const float*)d_in[11];
    const float* bend = (const float*)d_in[12];

    if (ws_size < WS_NEEDED) {
        lstm_fused<<<dim3(NN * 2), dim3(NTH), 0, stream>>>(
            x, Wih0, Whh0, bih0, bhh0, Wih1, Whh1, bih1, bhh1,
            wlin, blin, wend, bend, (float*)d_out);
        return;
    }

    short* wfrag = (short*)d_ws;
    short* xfrag = wfrag + WFRAG_ELEMS;

    prep_w<<<dim3((NN * NKT * NMT * 64 + 255) / 256), dim3(256), 0, stream>>>(
        Wih0, Whh0, bih0, bhh0, Wih1, Whh1, bih1, bhh1, wfrag);
    prep_x<<<dim3((NN * TT * 4 * 64 + 255) / 256), dim3(256), 0, stream>>>(x, xfrag);
    lstm_mfma4<<<dim3(NN * 2), dim3(1024), LDS_BYTES, stream>>>(
        wfrag, xfrag, wlin, blin, wend, bend, (float*)d_out);
}